// Round 6
// baseline (288.967 us; speedup 1.0000x reference)
//
#include <hip/hip_runtime.h>

#define S_LEN 1024
#define HSZ   1024
#define NHEAD 16
#define HD    64
#define BATCH 2
#define MROWS 2048   // BATCH * S_LEN
#define LOG2E 1.4426950408889634f
#define M0L2  72.134752044448f   // 50.0 * LOG2E  (fixed softmax shift, exact here)

typedef unsigned short u16;
typedef __attribute__((ext_vector_type(8))) short short8;
typedef __attribute__((ext_vector_type(4))) short short4v;
typedef __attribute__((ext_vector_type(4))) float f32x4;

#define MFMA_BF16(a, b, c) __builtin_amdgcn_mfma_f32_16x16x32_bf16((a), (b), (c), 0, 0, 0)

__device__ __forceinline__ u16 f2bf(float f) {
    union { float f; unsigned u; } c; c.f = f;
    unsigned u = c.u;
    u += 0x7fffu + ((u >> 16) & 1u);   // RNE (sign-safe)
    return (u16)(u >> 16);
}
__device__ __forceinline__ float bf2f(u16 s) {
    union { unsigned u; float f; } c; c.u = ((unsigned)s) << 16;
    return c.f;
}
__device__ __forceinline__ short8 ld8(const u16* p) {
    return *reinterpret_cast<const short8*>(p);
}
__device__ __forceinline__ void gld16(const u16* g, u16* l) {
    __builtin_amdgcn_global_load_lds(
        (const __attribute__((address_space(1))) unsigned int*)g,
        (__attribute__((address_space(3))) unsigned int*)l, 16, 0, 0);
}
// 8-chunk row (BK=64 tiles): chunk(row,cb) at row*8 + (cb^(row&7))
__device__ __forceinline__ int frag_off(int row, int cbb) {
    return (((row << 3) | (cbb ^ (row & 7))) << 3);
}
// 16-chunk row (BK=128 tiles): chunk(row,cb) at row*16 + (cb^(row&15))
__device__ __forceinline__ int frag_off16(int row, int cbb) {
    return (((row << 4) | (cbb ^ (row & 15))) << 3);
}

// ---------------------------------------------------------------------------
// GEMM core: C[(MT*32) x 128] += A * B^T, BK=128 (half the barriers of BK=64).
// 4 waves 2x2; wave tile (MT*16) x 64. LDS: A (MT*8KB) + B (32KB).
// ---------------------------------------------------------------------------
template<int MT>
__device__ __forceinline__ void gemm_tile(const u16* __restrict__ Ag,
                                          const u16* __restrict__ Bg,
                                          int klen, u16* As, u16* Bs,
                                          f32x4 (&acc)[MT][4]) {
    const int tid  = threadIdx.x;
    const int wave = tid >> 6, lane = tid & 63;
    const int lr = lane & 15, grp = lane >> 4;
    const int wm = wave >> 1, wn = wave & 1;

#pragma unroll
    for (int mt = 0; mt < MT; mt++)
#pragma unroll
        for (int nt = 0; nt < 4; nt++)
            acc[mt][nt] = (f32x4){0.f, 0.f, 0.f, 0.f};

    for (int k0 = 0; k0 < klen; k0 += 128) {
        __syncthreads();
#pragma unroll
        for (int j = 0; j < 2 * MT; j++) {   // A: MT*32 rows x 16 chunks
            int c = j * 256 + tid, row = c >> 4, cb = (c & 15) ^ (row & 15);
            gld16(Ag + (size_t)row * HSZ + k0 + cb * 8, As + c * 8);
        }
#pragma unroll
        for (int j = 0; j < 8; j++) {        // B: 128 rows x 16 chunks
            int c = j * 256 + tid, row = c >> 4, cb = (c & 15) ^ (row & 15);
            gld16(Bg + (size_t)row * HSZ + k0 + cb * 8, Bs + c * 8);
        }
        __syncthreads();

#pragma unroll
        for (int h = 0; h < 4; h++) {
            const int cbb = h * 4 + grp;
            short8 af[MT], bf[4];
#pragma unroll
            for (int mt = 0; mt < MT; mt++)
                af[mt] = ld8(As + frag_off16(wm * (MT * 16) + mt * 16 + lr, cbb));
#pragma unroll
            for (int nt = 0; nt < 4; nt++)
                bf[nt] = ld8(Bs + frag_off16(wn * 64 + nt * 16 + lr, cbb));
#pragma unroll
            for (int mt = 0; mt < MT; mt++)
#pragma unroll
                for (int nt = 0; nt < 4; nt++)
                    acc[mt][nt] = MFMA_BF16(af[mt], bf[nt], acc[mt][nt]);
        }
    }
}

// ---------------------------------------------------------------------------
// 1) fp32 -> bf16 conversion
// ---------------------------------------------------------------------------
__global__ __launch_bounds__(256)
void convert_kernel(const float* __restrict__ x,  const float* __restrict__ wq,
                    const float* __restrict__ wk, const float* __restrict__ wv,
                    const float* __restrict__ wo, u16* __restrict__ dst) {
    const int XV = (MROWS * HSZ) / 4;
    const int WV = (HSZ * HSZ) / 4;
    int vid = blockIdx.x * 256 + threadIdx.x;
    const float* src; int off;
    if (vid < XV)            { src = x;  off = vid; }
    else if (vid < XV + WV)  { src = wq; off = vid - XV; }
    else if (vid < XV + 2*WV){ src = wk; off = vid - XV - WV; }
    else if (vid < XV + 3*WV){ src = wv; off = vid - XV - 2*WV; }
    else                     { src = wo; off = vid - XV - 3*WV; }
    float4 v = reinterpret_cast<const float4*>(src)[off];
    ushort4 o;
    o.x = f2bf(v.x); o.y = f2bf(v.y); o.z = f2bf(v.z); o.w = f2bf(v.w);
    reinterpret_cast<ushort4*>(dst)[vid] = o;
}

// ---------------------------------------------------------------------------
// 2) Fused QKV GEMM, 64x128 tiles, BK=128. grid (24, 32).
//    V gets the key-mask folded in; written transposed [B,NH,D,S].
// ---------------------------------------------------------------------------
__global__ __launch_bounds__(256)
void qkv_gemm(const u16* __restrict__ xb,
              const u16* __restrict__ wqb, const u16* __restrict__ wkb,
              const u16* __restrict__ wvb,
              const float* __restrict__ bq, const float* __restrict__ bk,
              const float* __restrict__ bv, const float* __restrict__ mask,
              u16* __restrict__ qout, u16* __restrict__ kout,
              u16* __restrict__ vtout) {
    __shared__ u16 As[64 * 128];    // 16 KB
    __shared__ u16 Bs[128 * 128];   // 32 KB
    const int ntile = blockIdx.x;              // 0..23
    const int mtile = blockIdx.y;              // 0..31
    const int p  = ntile >> 3;
    const int m0 = mtile * 64;
    const int nw = (ntile & 7) * 128;
    const u16*  W    = (p == 0) ? wqb : (p == 1) ? wkb : wvb;
    const float* bias = (p == 0) ? bq : (p == 1) ? bk : bv;

    f32x4 acc[2][4];
    gemm_tile<2>(xb + (size_t)m0 * HSZ, W + (size_t)nw * HSZ, HSZ, As, Bs, acc);

    const int wave = threadIdx.x >> 6, lane = threadIdx.x & 63;
    const int lr = lane & 15, grp = lane >> 4;
    const int wm = wave >> 1, wn = wave & 1;
#pragma unroll
    for (int mt = 0; mt < 2; mt++)
#pragma unroll
        for (int nt = 0; nt < 4; nt++)
#pragma unroll
            for (int r = 0; r < 4; r++) {
                int m = m0 + wm * 32 + mt * 16 + grp * 4 + r;
                int o = nw + wn * 64 + nt * 16 + lr;
                float val = acc[mt][nt][r] + bias[o];
                int b = m >> 10, s = m & 1023, hh = o >> 6, d = o & 63;
                if (p == 0)
                    qout[(((size_t)(b * NHEAD + hh)) * S_LEN + s) * HD + d] = f2bf(val);
                else if (p == 1)
                    kout[(((size_t)(b * NHEAD + hh)) * S_LEN + s) * HD + d] = f2bf(val);
                else  // fold key-mask into V (denominator stays unmasked)
                    vtout[(((size_t)(b * NHEAD + hh)) * HD + d) * S_LEN + s] =
                        f2bf(val * mask[m]);
            }
}

// ---------------------------------------------------------------------------
// 3) Attention v4: k-split x2, fixed shift, register-pipelined gumbel loads,
//    denominator via ones-MFMA, constant-folded transcendentals.
//    Sign trick: w = rcp(log2 u) < 0 scales p, l, O by the same negative
//    constant; the O/l ratio in combine_kernel cancels it exactly.
// ---------------------------------------------------------------------------
__global__ __launch_bounds__(256, 4)
void attn_kernel(const u16* __restrict__ qb, const u16* __restrict__ kb,
                 const u16* __restrict__ vt, const float* __restrict__ gumbel,
                 u16* __restrict__ po, float* __restrict__ pl) {
    const int bh   = blockIdx.y;
    const int qt   = blockIdx.x;
    const int half = blockIdx.z;
    const int q0 = qt * 64, kbase = half * 512;
    const int tid = threadIdx.x;
    const int wave = tid >> 6, lane = tid & 63;
    const int lr = lane & 15, grp = lane >> 4;

    const u16* Q = qb + (size_t)bh * S_LEN * HD;
    const u16* K = kb + (size_t)bh * S_LEN * HD;
    const u16* V = vt + (size_t)bh * HD * S_LEN;
    const float* G = gumbel + (size_t)bh * S_LEN * S_LEN;
    const int qw = q0 + wave * 16;

    __shared__ u16 Ks[64 * 64];        // 8 KB
    __shared__ u16 Vs[64 * 64];        // 8 KB
    __shared__ u16 pbuf[4 * 16 * 68];  // 8.5 KB, row stride 68

    u16* pw = pbuf + wave * (16 * 68);

    short8 aq0 = ld8(Q + (size_t)(qw + lr) * HD + grp * 8);
    short8 aq1 = ld8(Q + (size_t)(qw + lr) * HD + 32 + grp * 8);

    short8 ones;
#pragma unroll
    for (int j = 0; j < 8; j++) ones[j] = (short)0x3F80;   // bf16 1.0

    f32x4 acco[4];
#pragma unroll
    for (int i = 0; i < 4; i++) acco[i] = (f32x4){0.f, 0.f, 0.f, 0.f};
    f32x4 accl = (f32x4){0.f, 0.f, 0.f, 0.f};

    const float* Grow[4];
#pragma unroll
    for (int r = 0; r < 4; r++)
        Grow[r] = G + (size_t)(qw + grp * 4 + r) * S_LEN + lr;

    // prologue: gumbel prefetch for iter 0
    float gpre[4][4];
#pragma unroll
    for (int kt = 0; kt < 4; kt++)
#pragma unroll
        for (int r = 0; r < 4; r++)
            gpre[kt][r] = Grow[r][kbase + kt * 16];

    for (int it = 0; it < 8; it++) {
        const int k0 = kbase + it * 64;
        __syncthreads();   // LDS reuse guard
        // stage K [64 k'][64 d] and V^T [64 d][64 k]
#pragma unroll
        for (int j = 0; j < 2; j++) {
            int c = j * 256 + tid, row = c >> 3, cb = (c & 7) ^ (row & 7);
            gld16(K + (size_t)(k0 + row) * HD + cb * 8, Ks + c * 8);
        }
#pragma unroll
        for (int j = 0; j < 2; j++) {
            int c = j * 256 + tid, row = c >> 3, cb = (c & 7) ^ (row & 7);
            gld16(V + (size_t)row * S_LEN + k0 + cb * 8, Vs + c * 8);
        }
        // w = rcp(log2 u)  (negative; constant -1/ln2 absorbed, cancels in O/l)
        float w[4][4];
#pragma unroll
        for (int kt = 0; kt < 4; kt++)
#pragma unroll
            for (int r = 0; r < 4; r++)
                w[kt][r] = __builtin_amdgcn_rcpf(__builtin_amdgcn_logf(gpre[kt][r]));
        __syncthreads();   // staging visible

        // issue next iter's gumbel loads; they land during compute below
        if (it < 7) {
#pragma unroll
            for (int kt = 0; kt < 4; kt++)
#pragma unroll
                for (int r = 0; r < 4; r++)
                    gpre[kt][r] = Grow[r][k0 + 64 + kt * 16];
        }

        // QK^T
        float sc[4][4];
#pragma unroll
        for (int kt = 0; kt < 4; kt++) {
            int row = kt * 16 + lr;
            f32x4 a = (f32x4){0.f, 0.f, 0.f, 0.f};
            a = MFMA_BF16(aq0, ld8(Ks + frag_off(row, grp)), a);
            a = MFMA_BF16(aq1, ld8(Ks + frag_off(row, 4 + grp)), a);
#pragma unroll
            for (int r = 0; r < 4; r++) sc[kt][r] = a[r];
        }

        // p = exp2(S*log2e - M0*log2e) * w  -> pbuf (bf16, negative values)
#pragma unroll
        for (int kt = 0; kt < 4; kt++)
#pragma unroll
            for (int r = 0; r < 4; r++) {
                float e = __builtin_amdgcn_exp2f(fmaf(sc[kt][r], LOG2E, -M0L2));
                pw[(grp * 4 + r) * 68 + kt * 16 + lr] = f2bf(e * w[kt][r]);
            }

        // P A-fragments (wave-local LDS, in-order; rows 8B-aligned -> 2x b64)
        short8 pa[2];
#pragma unroll
        for (int ks = 0; ks < 2; ks++) {
            const u16* pp = pw + lr * 68 + ks * 32 + grp * 8;
            short4v lo = *reinterpret_cast<const short4v*>(pp);
            short4v hi = *reinterpret_cast<const short4v*>(pp + 4);
            pa[ks] = __builtin_shufflevector(lo, hi, 0, 1, 2, 3, 4, 5, 6, 7);
        }

        // PV (V pre-masked) + denominator via ones-MFMA
#pragma unroll
        for (int nt = 0; nt < 4; nt++) {
            int row = nt * 16 + lr;
#pragma unroll
            for (int ks = 0; ks < 2; ks++)
                acco[nt] = MFMA_BF16(pa[ks], ld8(Vs + frag_off(row, ks * 4 + grp)),
                                     acco[nt]);
        }
#pragma unroll
        for (int ks = 0; ks < 2; ks++)
            accl = MFMA_BF16(pa[ks], ones, accl);
    }

    const int qidx = ((half * 32 + bh) * 16 + qt) * 64 + wave * 16 + grp * 4;
    if (lr == 0) {
#pragma unroll
        for (int r = 0; r < 4; r++) pl[qidx + r] = accl[r];
    }
#pragma unroll
    for (int nt = 0; nt < 4; nt++)
#pragma unroll
        for (int r = 0; r < 4; r++)
            po[(size_t)(qidx + r) * 64 + nt * 16 + lr] = f2bf(acco[nt][r]);
}

// ---------------------------------------------------------------------------
// 3b) Combine halves: ctx = (O0+O1)/(l0+l1) * mask_q  (signs cancel)
// ---------------------------------------------------------------------------
__global__ __launch_bounds__(256)
void combine_kernel(const u16* __restrict__ po, const float* __restrict__ pl,
                    const float* __restrict__ mask, u16* __restrict__ ctx) {
    const int qt = blockIdx.x, bh = blockIdx.y;
    const int b = bh >> 4, h = bh & 15;
    const int q = threadIdx.x >> 2;
    const int dc = (threadIdx.x & 3) * 16;
    const int i0 = ((0 * 32 + bh) * 16 + qt) * 64 + q;
    const int i1 = ((1 * 32 + bh) * 16 + qt) * 64 + q;
    float l = pl[i0] + pl[i1];
    float mq = mask[b * S_LEN + qt * 64 + q] / l;
    u16* dst = ctx + ((size_t)(b * S_LEN + qt * 64 + q)) * HSZ + h * 64 + dc;
#pragma unroll
    for (int c = 0; c < 2; c++) {
        short8 a = ld8(po + (size_t)i0 * 64 + dc + c * 8);
        short8 bm = ld8(po + (size_t)i1 * 64 + dc + c * 8);
        short8 o;
#pragma unroll
        for (int j = 0; j < 8; j++)
            o[j] = (short)f2bf((bf2f((u16)a[j]) + bf2f((u16)bm[j])) * mq);
        *reinterpret_cast<short8*>(dst + c * 8) = o;
    }
}

// ---------------------------------------------------------------------------
// 4) O-projection, split-k x2, BK=128. grid (8, 32, 2).
// ---------------------------------------------------------------------------
__global__ __launch_bounds__(256)
void oproj_gemm(const u16* __restrict__ A, const u16* __restrict__ W,
                float* __restrict__ part0, float* __restrict__ part1) {
    __shared__ u16 As[64 * 128];    // 16 KB
    __shared__ u16 Bs[128 * 128];   // 32 KB
    const int ntile = blockIdx.x;  // 0..7
    const int mtile = blockIdx.y;  // 0..31
    const int z     = blockIdx.z;
    const int m0 = mtile * 64, n0 = ntile * 128, koff = z * 512;

    f32x4 acc[2][4];
    gemm_tile<2>(A + (size_t)m0 * HSZ + koff, W + (size_t)n0 * HSZ + koff,
                 512, As, Bs, acc);

    float* dst = z ? part1 : part0;
    const int wave = threadIdx.x >> 6, lane = threadIdx.x & 63;
    const int lr = lane & 15, grp = lane >> 4;
    const int wm = wave >> 1, wn = wave & 1;
#pragma unroll
    for (int mt = 0; mt < 2; mt++)
#pragma unroll
        for (int nt = 0; nt < 4; nt++)
#pragma unroll
            for (int r = 0; r < 4; r++) {
                int m = m0 + wm * 32 + mt * 16 + grp * 4 + r;
                int o = n0 + wn * 64 + nt * 16 + lr;
                dst[(size_t)m * HSZ + o] = acc[mt][nt][r];
            }
}

// ---------------------------------------------------------------------------
// 5) Fused residual + LayerNorm
// ---------------------------------------------------------------------------
__global__ __launch_bounds__(256)
void ln_kernel(const float* __restrict__ part0, const float* __restrict__ part1,
               const float* __restrict__ xin, const float* __restrict__ bo,
               const float* __restrict__ gamma, const float* __restrict__ beta,
               float* __restrict__ out) {
    const int row = blockIdx.x;
    const int tid = threadIdx.x;
    const size_t base = (size_t)row * (HSZ / 4);

    float4 p0 = reinterpret_cast<const float4*>(part0)[base + tid];
    float4 p1 = reinterpret_cast<const float4*>(part1)[base + tid];
    float4 xr = reinterpret_cast<const float4*>(xin)[base + tid];
    float4 bb = reinterpret_cast<const float4*>(bo)[tid];
    float4 v;
    v.x = p0.x + p1.x + xr.x + bb.x;
    v.y = p0.y + p1.y + xr.y + bb.y;
    v.z = p0.z + p1.z + xr.z + bb.z;
    v.w = p0.w + p1.w + xr.w + bb.w;

    float s  = v.x + v.y + v.z + v.w;
    float ss = v.x * v.x + v.y * v.y + v.z * v.z + v.w * v.w;
#pragma unroll
    for (int off = 1; off < 64; off <<= 1) {
        s  += __shfl_xor(s, off, 64);
        ss += __shfl_xor(ss, off, 64);
    }
    __shared__ float red[8];
    int wave = tid >> 6, lane = tid & 63;
    if (lane == 0) { red[wave] = s; red[4 + wave] = ss; }
    __syncthreads();
    s  = red[0] + red[1] + red[2] + red[3];
    ss = red[4] + red[5] + red[6] + red[7];
    float mu  = s * (1.f / HSZ);
    float var = ss * (1.f / HSZ) - mu * mu;
    float rstd = rsqrtf(var + 1e-5f);

    float4 g  = reinterpret_cast<const float4*>(gamma)[tid];
    float4 be = reinterpret_cast<const float4*>(beta)[tid];
    float4 o;
    o.x = (v.x - mu) * rstd * g.x + be.x;
    o.y = (v.y - mu) * rstd * g.y + be.y;
    o.z = (v.z - mu) * rstd * g.z + be.z;
    o.w = (v.w - mu) * rstd * g.w + be.w;
    reinterpret_cast<float4*>(out)[base + tid] = o;
}

// ---------------------------------------------------------------------------
extern "C" void kernel_launch(void* const* d_in, const int* in_sizes, int n_in,
                              void* d_out, int out_size, void* d_ws, size_t ws_size,
                              hipStream_t stream) {
    (void)in_sizes; (void)n_in; (void)out_size; (void)ws_size;
    const float* x     = (const float*)d_in[0];
    const float* mask  = (const float*)d_in[1];
    const float* gum   = (const float*)d_in[2];
    const float* Wq    = (const float*)d_in[3];
    const float* bq    = (const float*)d_in[4];
    const float* Wk    = (const float*)d_in[5];
    const float* bk    = (const float*)d_in[6];
    const float* Wv    = (const float*)d_in[7];
    const float* bv    = (const float*)d_in[8];
    const float* Wo    = (const float*)d_in[9];
    const float* bo    = (const float*)d_in[10];
    const float* gamma = (const float*)d_in[11];
    const float* beta  = (const float*)d_in[12];
    float* out = (float*)d_out;

    u16* xb  = (u16*)d_ws;
    u16* wqb = xb  + 2097152;
    u16* wkb = wqb + 1048576;
    u16* wvb = wkb + 1048576;
    u16* wob = wvb + 1048576;
    u16* qb  = wob + 1048576;
    u16* kb  = qb  + 2097152;
    u16* vt  = kb  + 2097152;
    u16* ctx = vt  + 2097152;
    float* part0 = (float*)(ctx + 2097152);          // 8 MB
    float* pl    = (float*)((char*)part0 + 8388608); // 256 KB
    u16*   po    = xb;                               // reuse (attn->combine)
    float* part1 = (float*)xb;                       // reuse (oproj->ln)

    convert_kernel<<<dim3(6144), dim3(256), 0, stream>>>(x, Wq, Wk, Wv, Wo, xb);
    qkv_gemm<<<dim3(24, 32), dim3(256), 0, stream>>>(xb, wqb, wkb, wvb,
                                                     bq, bk, bv, mask,
                                                     qb, kb, vt);
    attn_kernel<<<dim3(16, 32, 2), dim3(256), 0, stream>>>(qb, kb, vt, gum, po, pl);
    combine_kernel<<<dim3(16, 32), dim3(256), 0, stream>>>(po, pl, mask, ctx);
    oproj_gemm<<<dim3(8, 32, 2), dim3(256), 0, stream>>>(ctx, wob, part0, part1);
    ln_kernel<<<dim3(2048), dim3(256), 0, stream>>>(part0, part1, x, bo,
                                                    gamma, beta, out);
}